// Round 4
// baseline (177.761 us; speedup 1.0000x reference)
//
#include <hip/hip_runtime.h>
#include <cstdint>
#include <cstddef>

#define AUDIO_DIM 512
#define TEXT_DIM  768
#define HIDDEN    512
#define BATCH     8
#define ALEN      2048
#define TLEN      512

typedef _Float16 half8 __attribute__((ext_vector_type(8)));
typedef _Float16 half4_t __attribute__((ext_vector_type(4)));
typedef float floatx4 __attribute__((ext_vector_type(4)));

#define AS1 __attribute__((address_space(1)))
#define AS3 __attribute__((address_space(3)))

// Async global->LDS, 16B per lane. LDS dest = wave-uniform base + lane*16.
__device__ __forceinline__ void gload_lds16(const void* g, void* l) {
    __builtin_amdgcn_global_load_lds((const AS1 void*)g, (AS3 void*)l, 16, 0, 0);
}

// XOR swizzle for 64B-row staged tiles: 16B chunk c of row r at slot c ^ swz(r).
__device__ __forceinline__ int swz(int r) { return (r >> 1) & 3; }

// ---------------------------------------------------------------------------
// prep: ONE kernel for all input conditioning.
//   blocks [0,8192)      : audio fp32 -> f16 (float4-vectorized)
//   blocks [8192,11264)  : text  fp32 -> f16
//   blocks [11264,11520) : Wq [512][512] -> Wq_t [512][512] f16 (transpose)
//   blocks [11520,11904) : Wk [768][512] -> Wk_t [512][768] f16
//   blocks [11904,12288) : Wv [768][512] -> Wv_t [512][768] f16
// ---------------------------------------------------------------------------
__global__ __launch_bounds__(256) void prep(
    const float* __restrict__ audio, const float* __restrict__ text,
    const float* __restrict__ Wq, const float* __restrict__ Wk,
    const float* __restrict__ Wv,
    _Float16* __restrict__ audio_h, _Float16* __restrict__ text_h,
    _Float16* __restrict__ Wq_t, _Float16* __restrict__ Wk_t,
    _Float16* __restrict__ Wv_t)
{
    __shared__ _Float16 tt[32 * 33];
    const int bid = blockIdx.x, tid = threadIdx.x;
    if (bid < 11264) {
        const float* src; _Float16* dst; int i;
        if (bid < 8192) { src = audio; dst = audio_h; i = bid * 256 + tid; }
        else            { src = text;  dst = text_h;  i = (bid - 8192) * 256 + tid; }
        float4 v = ((const float4*)src)[i];
        half4_t h;
        h.x = (_Float16)v.x; h.y = (_Float16)v.y; h.z = (_Float16)v.z; h.w = (_Float16)v.w;
        ((half4_t*)dst)[i] = h;
    } else {
        const float* src; _Float16* dst; int R, lb;
        if (bid < 11520)      { lb = bid - 11264; src = Wq; dst = Wq_t; R = 512; }
        else if (bid < 11904) { lb = bid - 11520; src = Wk; dst = Wk_t; R = 768; }
        else                  { lb = bid - 11904; src = Wv; dst = Wv_t; R = 768; }
        const int C = 512;
        const int c0 = (lb & 15) * 32, r0 = (lb >> 4) * 32;
        const int tx = tid & 31, ty = tid >> 5;   // 32 x 8
#pragma unroll
        for (int i = 0; i < 4; i++) {
            int r = ty + i * 8;
            tt[r * 33 + tx] = (_Float16)src[(size_t)(r0 + r) * C + c0 + tx];
        }
        __syncthreads();
#pragma unroll
        for (int i = 0; i < 4; i++) {
            int r = ty + i * 8;
            dst[(size_t)(c0 + r) * R + r0 + tx] = tt[tx * 33 + r];
        }
    }
}

// ---------------------------------------------------------------------------
// Shared f16 MFMA GEMM body: C tile at (m0,n0) = A[M,K] @ Bt[N,K]^T (+bias).
// 128x128 tile, BK=32, 4 waves, wave = 64x64 via 4x4 MFMA 16x16x32 tiles.
// ---------------------------------------------------------------------------
template <bool OUT16, bool ROWBIAS>
__device__ __forceinline__ void gemm_body(
    const _Float16* __restrict__ A, const _Float16* __restrict__ Bt,
    const float* __restrict__ bias, void* __restrict__ Cp,
    int N, int K, int m0, int n0, _Float16* Asm, _Float16* Bsm)
{
    const int tid = threadIdx.x;
    const int l = tid & 63, w = tid >> 6;
    const int wm = w >> 1, wn = w & 1;
    const int srow = l >> 2, sj = l & 3;       // staging: lane -> (row, chunk-slot)
    const int q = l >> 4, c16 = l & 15;        // MFMA lane coords

    floatx4 acc[4][4] = {};

    for (int k0 = 0; k0 < K; k0 += 32) {
        if (k0) __syncthreads();
#pragma unroll
        for (int i = 0; i < 2; i++) {
            int rb = (w * 2 + i) * 16;
            int r = rb + srow;
            int cc = sj ^ swz(r);
            gload_lds16(A + (size_t)(m0 + r) * K + k0 + cc * 8, Asm + rb * 32);
            gload_lds16(Bt + (size_t)(n0 + r) * K + k0 + cc * 8, Bsm + rb * 32);
        }
        __syncthreads();

        half8 af[4], bf[4];
#pragma unroll
        for (int t = 0; t < 4; t++) {
            int rA = wm * 64 + t * 16 + c16;
            af[t] = *(const half8*)&Asm[rA * 32 + ((q ^ swz(rA)) << 3)];
            int rB = wn * 64 + t * 16 + c16;
            bf[t] = *(const half8*)&Bsm[rB * 32 + ((q ^ swz(rB)) << 3)];
        }
#pragma unroll
        for (int mi = 0; mi < 4; mi++)
#pragma unroll
            for (int ni = 0; ni < 4; ni++)
                acc[mi][ni] = __builtin_amdgcn_mfma_f32_16x16x32_f16(
                    af[mi], bf[ni], acc[mi][ni], 0, 0, 0);
    }

    // Epilogue. C/D layout per 16x16 tile: col = c16, row = q*4 + reg.
    if (OUT16) {
        float bcol[4];
        float brow[4][4];
        if (!ROWBIAS) {
#pragma unroll
            for (int ni = 0; ni < 4; ni++)
                bcol[ni] = bias[n0 + wn * 64 + ni * 16 + c16];
        } else {
#pragma unroll
            for (int mi = 0; mi < 4; mi++) {
                float4 b4 = *(const float4*)&bias[m0 + wm * 64 + mi * 16 + q * 4];
                brow[mi][0] = b4.x; brow[mi][1] = b4.y;
                brow[mi][2] = b4.z; brow[mi][3] = b4.w;
            }
        }
        _Float16* C = (_Float16*)Cp;
#pragma unroll
        for (int ni = 0; ni < 4; ni++) {
            int col = n0 + wn * 64 + ni * 16 + c16;
#pragma unroll
            for (int mi = 0; mi < 4; mi++) {
                int row = m0 + wm * 64 + mi * 16 + q * 4;
#pragma unroll
                for (int r = 0; r < 4; r++) {
                    float b = ROWBIAS ? brow[mi][r] : bcol[ni];
                    C[(size_t)(row + r) * N + col] = (_Float16)(acc[mi][ni][r] + b);
                }
            }
        }
    } else {
        float* C = (float*)Cp;
#pragma unroll
        for (int ni = 0; ni < 4; ni++) {
            int col = n0 + wn * 64 + ni * 16 + c16;
#pragma unroll
            for (int mi = 0; mi < 4; mi++) {
                int row = m0 + wm * 64 + mi * 16 + q * 4;
#pragma unroll
                for (int r = 0; r < 4; r++)
                    C[(size_t)(row + r) * N + col] = acc[mi][ni][r];
            }
        }
    }
}

// ---------------------------------------------------------------------------
// qkv_gemm: ONE kernel, 768 blocks, demuxed:
//   [0,512)   Q  = audio_h @ Wq_t^T + bq                  -> Qh f16 (in ws)
//   [512,640) K  = text_h @ Wk_t^T + bk                   -> Kh f16
//   [640,768) V^T[h][t] = Wv_t @ text_h(b)^T + bv[h] (row bias) -> Vt f16
// ---------------------------------------------------------------------------
__global__ __launch_bounds__(256, 2) void qkv_gemm(
    const _Float16* __restrict__ audio_h, const _Float16* __restrict__ text_h,
    const _Float16* __restrict__ Wq_t, const _Float16* __restrict__ Wk_t,
    const _Float16* __restrict__ Wv_t,
    const float* __restrict__ bq, const float* __restrict__ bk,
    const float* __restrict__ bv,
    _Float16* __restrict__ Qh, _Float16* __restrict__ Kh,
    _Float16* __restrict__ Vt)
{
    __shared__ __align__(16) _Float16 Asm[128 * 32];
    __shared__ __align__(16) _Float16 Bsm[128 * 32];
    const int bid = blockIdx.x;
    if (bid < 512) {
        gemm_body<true, false>(audio_h, Wq_t, bq, Qh, 512, 512,
                               (bid >> 2) * 128, (bid & 3) * 128, Asm, Bsm);
    } else if (bid < 640) {
        int lb = bid - 512;
        gemm_body<true, false>(text_h, Wk_t, bk, Kh, 512, 768,
                               (lb >> 2) * 128, (lb & 3) * 128, Asm, Bsm);
    } else {
        int lb = bid - 640;
        int z = lb >> 4, by = (lb >> 2) & 3, bx = lb & 3;
        gemm_body<true, true>(Wv_t, text_h + (size_t)z * 393216, bv,
                              Vt + (size_t)z * 262144, 512, 768,
                              by * 128, bx * 128, Asm, Bsm);
    }
}

// ---------------------------------------------------------------------------
// attn_fused: per block = (batch, 32 Q-rows) x all 512 keys, flash-style.
//   Phase 1: S = (Q @ K^T)*scale, masked  (acc[2][8] per wave, wave owns
//            key-cols [w*128, w*128+128))
//   Phase 2: row softmax (shuffle + cross-wave LDS reduce)
//   Phase 3: P (f16, normalized) -> swizzled LDS buffer Pl
//   Phase 4: out = P @ V via MFMA; A-frags from Pl, B-frags from staged V^T
//            (V^T reuses the K staging buffer). fp32 out to d_out.
// LDS: Qs 2K + KV 32K + Pl 34K + red 1K = 69 KB -> 2 blocks/CU.
// Pl layout: row stride 544 halfs (1088 B: odd rows +16 banks); within each
// 4-aligned 16B-chunk group, chunk c stored at c ^ ((row>>1)&3).
// Write key ((mi*16+q*4+r)>>1)&3 == read key ((mi*16+c16)>>1)&3 == (c16>>1)&3.
// ---------------------------------------------------------------------------
#define QT 32
#define PSTR 544

__global__ __launch_bounds__(256, 2) void attn_fused(
    const _Float16* __restrict__ Qh, const _Float16* __restrict__ Kh,
    const _Float16* __restrict__ Vt, const int* __restrict__ mask,
    float* __restrict__ out)
{
    __shared__ __align__(16) _Float16 Qs[QT * 32];     // 2 KB
    __shared__ __align__(16) _Float16 KV[512 * 32];    // 32 KB (K, then V^T)
    __shared__ __align__(16) _Float16 Pl[QT * PSTR];   // 34 KB
    __shared__ float red[4][QT];
    __shared__ float red2[4][QT];
    const int tid = threadIdx.x, l = tid & 63, w = tid >> 6;
    const int b = blockIdx.y, a0 = blockIdx.x * QT;
    const _Float16* Qb = Qh + (size_t)(b * ALEN + a0) * HIDDEN;
    const _Float16* Kb = Kh + (size_t)b * TLEN * HIDDEN;
    const _Float16* Vb = Vt + (size_t)b * HIDDEN * TLEN;   // [h][t]
    const int srow = l >> 2, sj = l & 3;
    const int q = l >> 4, c16 = l & 15;

    // ---- Phase 1: scores ----
    floatx4 acc[2][8] = {};
    for (int k0 = 0; k0 < HIDDEN; k0 += 32) {
        if (k0) __syncthreads();
        if (w < 2) {   // Q tile: 32 rows = 2 wave-issues
            int rb = w * 16;
            int r = rb + srow;
            int cc = sj ^ swz(r);
            gload_lds16(Qb + (size_t)r * HIDDEN + k0 + cc * 8, Qs + rb * 32);
        }
#pragma unroll
        for (int i = 0; i < 8; i++) {   // K tile: 512 rows
            int rb = (w * 8 + i) * 16;
            int r = rb + srow;
            int cc = sj ^ swz(r);
            gload_lds16(Kb + (size_t)r * HIDDEN + k0 + cc * 8, KV + rb * 32);
        }
        __syncthreads();

        half8 af[2], bf[8];
#pragma unroll
        for (int t = 0; t < 2; t++) {
            int rA = t * 16 + c16;
            af[t] = *(const half8*)&Qs[rA * 32 + ((q ^ swz(rA)) << 3)];
        }
#pragma unroll
        for (int t = 0; t < 8; t++) {
            int rB = w * 128 + t * 16 + c16;
            bf[t] = *(const half8*)&KV[rB * 32 + ((q ^ swz(rB)) << 3)];
        }
#pragma unroll
        for (int mi = 0; mi < 2; mi++)
#pragma unroll
            for (int ni = 0; ni < 8; ni++)
                acc[mi][ni] = __builtin_amdgcn_mfma_f32_16x16x32_f16(
                    af[mi], bf[ni], acc[mi][ni], 0, 0, 0);
    }

    // ---- Phase 2: mask + softmax ----
    const float scale = 0.044194173824159216f;   // 512^-0.5
    int mv[8];
#pragma unroll
    for (int ni = 0; ni < 8; ni++)
        mv[ni] = mask[b * TLEN + w * 128 + ni * 16 + c16];
#pragma unroll
    for (int mi = 0; mi < 2; mi++)
#pragma unroll
        for (int ni = 0; ni < 8; ni++)
#pragma unroll
            for (int r = 0; r < 4; r++)
                acc[mi][ni][r] = mv[ni] ? acc[mi][ni][r] * scale : -1e30f;

    float mx[2][4];
#pragma unroll
    for (int mi = 0; mi < 2; mi++)
#pragma unroll
        for (int r = 0; r < 4; r++) {
            float m = -1e30f;
#pragma unroll
            for (int ni = 0; ni < 8; ni++) m = fmaxf(m, acc[mi][ni][r]);
#pragma unroll
            for (int off = 1; off <= 8; off <<= 1) m = fmaxf(m, __shfl_xor(m, off));
            mx[mi][r] = m;
        }
    if (c16 == 0)
#pragma unroll
        for (int mi = 0; mi < 2; mi++)
#pragma unroll
            for (int r = 0; r < 4; r++) red[w][mi * 16 + q * 4 + r] = mx[mi][r];
    __syncthreads();
#pragma unroll
    for (int mi = 0; mi < 2; mi++)
#pragma unroll
        for (int r = 0; r < 4; r++) {
            int row = mi * 16 + q * 4 + r;
            mx[mi][r] = fmaxf(fmaxf(red[0][row], red[1][row]),
                              fmaxf(red[2][row], red[3][row]));
        }

    float sm[2][4];
#pragma unroll
    for (int mi = 0; mi < 2; mi++)
#pragma unroll
        for (int r = 0; r < 4; r++) {
            float s = 0.f;
#pragma unroll
            for (int ni = 0; ni < 8; ni++) {
                float e = __expf(acc[mi][ni][r] - mx[mi][r]);
                acc[mi][ni][r] = e;
                s += e;
            }
#pragma unroll
            for (int off = 1; off <= 8; off <<= 1) s += __shfl_xor(s, off);
            sm[mi][r] = s;
        }
    if (c16 == 0)
#pragma unroll
        for (int mi = 0; mi < 2; mi++)
#pragma unroll
            for (int r = 0; r < 4; r++) red2[w][mi * 16 + q * 4 + r] = sm[mi][r];
    __syncthreads();

    // ---- Phase 3: write normalized P (f16) into swizzled Pl ----
#pragma unroll
    for (int mi = 0; mi < 2; mi++)
#pragma unroll
        for (int r = 0; r < 4; r++) {
            int row = mi * 16 + q * 4 + r;
            float inv = 1.f / (red2[0][row] + red2[1][row] + red2[2][row] + red2[3][row]);
#pragma unroll
            for (int ni = 0; ni < 8; ni++) {
                int t = w * 128 + ni * 16 + c16;
                int chunk = t >> 3;
                int chunkS = (chunk & ~3) | ((chunk & 3) ^ ((row >> 1) & 3));
                Pl[row * PSTR + chunkS * 8 + (t & 7)] = (_Float16)(acc[mi][ni][r] * inv);
            }
        }
    __syncthreads();

    // ---- Phase 4: out = P @ V ----
    floatx4 oacc[2][8] = {};
    for (int k0 = 0; k0 < TLEN; k0 += 32) {
        if (k0) __syncthreads();
#pragma unroll
        for (int i = 0; i < 8; i++) {   // V^T tile: 512 h-rows x 32 t
            int rb = (w * 8 + i) * 16;
            int r = rb + srow;
            int cc = sj ^ swz(r);
            gload_lds16(Vb + (size_t)r * TLEN + k0 + cc * 8, KV + rb * 32);
        }
        __syncthreads();

        half8 pf[2], vf[8];
#pragma unroll
        for (int mi = 0; mi < 2; mi++) {
            int row = mi * 16 + c16;
            int chunkS = (k0 >> 3) + (q ^ ((c16 >> 1) & 3));
            pf[mi] = *(const half8*)&Pl[row * PSTR + chunkS * 8];
        }
#pragma unroll
        for (int t = 0; t < 8; t++) {
            int rB = w * 128 + t * 16 + c16;
            vf[t] = *(const half8*)&KV[rB * 32 + ((q ^ swz(rB)) << 3)];
        }
#pragma unroll
        for (int mi = 0; mi < 2; mi++)
#pragma unroll
            for (int ni = 0; ni < 8; ni++)
                oacc[mi][ni] = __builtin_amdgcn_mfma_f32_16x16x32_f16(
                    pf[mi], vf[ni], oacc[mi][ni], 0, 0, 0);
    }

    // ---- Epilogue: fp32 store ----
#pragma unroll
    for (int ni = 0; ni < 8; ni++) {
        int col = w * 128 + ni * 16 + c16;
#pragma unroll
        for (int mi = 0; mi < 2; mi++) {
            int row = mi * 16 + q * 4;
#pragma unroll
            for (int r = 0; r < 4; r++)
                out[(size_t)(b * ALEN + a0 + row + r) * HIDDEN + col] =
                    oacc[mi][ni][r];
        }
    }
}

// ---------------------------------------------------------------------------
extern "C" void kernel_launch(void* const* d_in, const int* in_sizes, int n_in,
                              void* d_out, int out_size, void* d_ws, size_t ws_size,
                              hipStream_t stream)
{
    const float* audio = (const float*)d_in[0];   // [8,2048,512]
    const float* text  = (const float*)d_in[1];   // [8,512,768]
    const float* Wq    = (const float*)d_in[2];   // [512,512]
    const float* bq    = (const float*)d_in[3];
    const float* Wk    = (const float*)d_in[4];   // [768,512]
    const float* bk    = (const float*)d_in[5];
    const float* Wv    = (const float*)d_in[6];   // [768,512]
    const float* bv    = (const float*)d_in[7];
    const int*   maskp = (const int*)d_in[8];     // [8,512]
    float* out = (float*)d_out;

    // audio_h lives in d_out (dead after qkv_gemm; attn_fused only WRITES d_out).
    _Float16* audio_h = (_Float16*)d_out;

    // ws layout (halfs), total 33.55 MB (< previous 37.75 MB usage)
    _Float16* ws16   = (_Float16*)d_ws;
    _Float16* text_h = ws16;                        // 3,145,728  [B*512][768]
    _Float16* Wq_t   = text_h + 3145728;            //   262,144  [512][512]
    _Float16* Wk_t   = Wq_t + 262144;               //   393,216  [512][768]
    _Float16* Wv_t   = Wk_t + 393216;               //   393,216  [512][768]
    _Float16* Kh     = Wv_t + 393216;               // 2,097,152  [B,512,512]
    _Float16* Vt     = Kh + 2097152;                // 2,097,152  [B,512(h),512(t)]
    _Float16* Qh     = Vt + 2097152;                // 8,388,608  [B,2048,512]

    // 1) all input conditioning
    prep<<<12288, 256, 0, stream>>>(audio, text, Wq, Wk, Wv,
                                    audio_h, text_h, Wq_t, Wk_t, Wv_t);
    // 2) Q + K + V^T GEMMs
    qkv_gemm<<<768, 256, 0, stream>>>(audio_h, text_h, Wq_t, Wk_t, Wv_t,
                                      bq, bk, bv, Qh, Kh, Vt);
    // 3) fused scores + softmax + PV
    attn_fused<<<dim3(ALEN / QT, BATCH), 256, 0, stream>>>(Qh, Kh, Vt, maskp, out);
}